// Round 3
// baseline (439.930 us; speedup 1.0000x reference)
//
#include <hip/hip_runtime.h>
#include <math.h>

#define NN 100000
#define EE 1600000
#define HID 64
#define BKT 391                 // ceil(NN/256) buckets of 256 nodes
#define SLAB 5504               // slab capacity per bucket (mean ~4092)
#define CHUNK_S 1024            // edges per workgroup in count/scatter passes
#define NCB ((EE + CHUNK_S - 1) / CHUNK_S)   // 1563
#define TB (NN / 16)            // 6250 transform blocks (4 waves x 4 nodes)

typedef _Float16 f16;
typedef _Float16 f16x2 __attribute__((ext_vector_type(2)));

__device__ __forceinline__ f16x2 u2h(unsigned u) { return __builtin_bit_cast(f16x2, u); }
__device__ __forceinline__ unsigned h2u(f16x2 h) { return __builtin_bit_cast(unsigned, h); }

#if defined(__has_builtin) && __has_builtin(__builtin_amdgcn_fdot2)
__device__ __forceinline__ float dot2(f16x2 a, f16x2 b, float c) {
    return __builtin_amdgcn_fdot2(a, b, c, false);
}
#else
__device__ __forceinline__ float dot2(f16x2 a, f16x2 b, float c) {
    c = fmaf((float)a.x, (float)b.x, c);
    return fmaf((float)a.y, (float)b.y, c);
}
#endif

// ========== K1: per-node degree count (blocks 0..NCB-1) =======================
// ========== || layer-0 transform + weight pack (blocks NCB..) =================
// r16: replaces the pairs-slab placement. Count = 1.6M global atomicAdd on
// cnt[100k] (random, ~16/node contention; L2 atomics), fully overlapped with
// the transform blocks that dominate this kernel.

__global__ void ct_kernel(const int* __restrict__ dst, int* __restrict__ cnt,
                          const float* __restrict__ h,
                          const float* __restrict__ Wn, const float* __restrict__ bn,
                          const float* __restrict__ Wr,
                          f16* __restrict__ hn, f16* __restrict__ hrb,
                          const float* __restrict__ Wn1, const float* __restrict__ Wr1,
                          const float* __restrict__ Wn2, const float* __restrict__ Wr2,
                          const float* __restrict__ Wp1, unsigned* __restrict__ w16) {
    int t = threadIdx.x;

    if (blockIdx.x < NCB) {
        int base = blockIdx.x * CHUNK_S;
#pragma unroll
        for (int j = 0; j < CHUNK_S / 256; ++j) {
            int i = base + j * 256 + t;
            if (i < EE) atomicAdd(&cnt[dst[i]], 1);
        }
        return;
    }

    int bb = blockIdx.x - NCB;

    // ---- f16 weight pack (first 40 transform blocks) ----
    if (bb < 40) {
        int id = bb * 256 + t;
        int mat = id >> 11;            // 0..4
        int p = (id >> 6) & 31;        // pair index
        int j = id & 63;               // output column
        const float* W = (mat == 0) ? Wn1 : (mat == 1) ? Wr1 :
                         (mat == 2) ? Wn2 : (mat == 3) ? Wr2 : Wp1;
        f16x2 v;
        v.x = (f16)W[(2 * p) * HID + j];
        v.y = (f16)W[(2 * p + 1) * HID + j];
        w16[id] = h2u(v);
    }

    // ---- layer-0 transform: 4 nodes/wave, lane = output column ----
    int lane = t & 63;
    int wid = (bb * 256 + t) >> 6;
    int m0 = __builtin_amdgcn_readfirstlane(wid << 2);
    const float* h0 = h + (size_t)m0 * 32;

    float an0 = 0.f, an1 = 0.f, an2 = 0.f, an3 = 0.f;
    float ar0 = 0.f, ar1 = 0.f, ar2 = 0.f, ar3 = 0.f;
#pragma unroll
    for (int k = 0; k < 32; ++k) {
        float wn = Wn[k * HID + lane];
        float wr = Wr[k * HID + lane];
        float hk0 = h0[k], hk1 = h0[32 + k], hk2 = h0[64 + k], hk3 = h0[96 + k];
        an0 = fmaf(hk0, wn, an0); ar0 = fmaf(hk0, wr, ar0);
        an1 = fmaf(hk1, wn, an1); ar1 = fmaf(hk1, wr, ar1);
        an2 = fmaf(hk2, wn, an2); ar2 = fmaf(hk2, wr, ar2);
        an3 = fmaf(hk3, wn, an3); ar3 = fmaf(hk3, wr, ar3);
    }
    float b = bn[lane];
    size_t o = (size_t)m0 * HID + lane;
    hn[o] = (f16)an0; hn[o + HID] = (f16)an1;
    hn[o + 2 * HID] = (f16)an2; hn[o + 3 * HID] = (f16)an3;
    hrb[o] = (f16)(ar0 + b); hrb[o + HID] = (f16)(ar1 + b);
    hrb[o + 2 * HID] = (f16)(ar2 + b); hrb[o + 3 * HID] = (f16)(ar3 + b);
}

// ========== K2: per-bucket exclusive scan -> rs/re/inv/cursor =================
// 391 blocks x 256 threads, 1KB I/O per block: ~3us. Bucket b's nodes get
// contiguous slots in [b*SLAB, b*SLAB+total). SLAB=5504 vs mean 4092 (22 sigma).

__global__ void scan_kernel(const int* __restrict__ cnt,
                            int* __restrict__ rs, int* __restrict__ re,
                            float* __restrict__ inv, int* __restrict__ cursor) {
    __shared__ int sc[256];
    int b = blockIdx.x;
    int t = threadIdx.x;
    int node = (b << 8) + t;
    int c = (node < NN) ? cnt[node] : 0;
    sc[t] = c;
    __syncthreads();
    for (int off = 1; off < 256; off <<= 1) {
        int u = (t >= off) ? sc[t - off] : 0;
        __syncthreads();
        sc[t] += u;
        __syncthreads();
    }
    int excl = sc[t] - c;
    if (node < NN) {
        int s0 = b * SLAB;
        int cap = s0 + SLAB;
        int start = s0 + excl; if (start > cap) start = cap;     // unreachable
        int end = start + c;   if (end > cap) end = cap;         // unreachable
        rs[node] = start;
        re[node] = end;
        inv[node] = (c > 0) ? (1.0f / (float)c) : 0.0f;
        cursor[node] = start;
    }
}

// ========== K3: edge scatter into CSR slots ===================================
// slot order within a node = atomic arrival order (sum reorder ~2^-11 rel jitter
// in the f16 accumulation; semantics match reference's unordered segment_sum).

__global__ void scat_kernel(const int* __restrict__ src, const int* __restrict__ dst,
                            int* __restrict__ cursor, int* __restrict__ col) {
    int t = threadIdx.x;
    int base = blockIdx.x * CHUNK_S;
#pragma unroll
    for (int j = 0; j < CHUNK_S / 256; ++j) {
        int i = base + j * 256 + t;
        if (i < EE) {
            int d = dst[i];
            int slot = atomicAdd(&cursor[d], 1);
            int cap = ((d >> 8) + 1) * SLAB;
            if (slot < cap) col[slot] = src[i];                  // guard unreachable
        }
    }
}

// ================= quarter-wave gather (device helper) =================
// Wave = 4 nodes: lane = (node quarter)<<4 | fl. Each lane loads uint2 (4 f16)
// of a neighbor row; 8-deep main loop (best measured, r12). Packed-f16
// accumulation (accuracy verified r13).
// r14 (shfl-broadcast 16-deep) FAILED +10%; r15 (LDS col stage) FAILED +5%:
// gather is NOT col-chain-bound — it is MSHR-x-latency bound (205MB rows/kernel
// at 3.8TB/s = ~60 lines in flight/CU at ~600cy L3 latency). Keep r13 form.

__device__ __forceinline__ void qgather(const uint2* __restrict__ rp,
                                        const int* __restrict__ col,
                                        int e, int en, int fl,
                                        f16x2& s0, f16x2& s1) {
    while (e + 8 <= en) {
        int c0 = col[e],     c1 = col[e + 1], c2 = col[e + 2], c3 = col[e + 3];
        int c4 = col[e + 4], c5 = col[e + 5], c6 = col[e + 6], c7 = col[e + 7];
        uint2 v0 = rp[(size_t)c0 * 16 + fl];
        uint2 v1 = rp[(size_t)c1 * 16 + fl];
        uint2 v2 = rp[(size_t)c2 * 16 + fl];
        uint2 v3 = rp[(size_t)c3 * 16 + fl];
        uint2 v4 = rp[(size_t)c4 * 16 + fl];
        uint2 v5 = rp[(size_t)c5 * 16 + fl];
        uint2 v6 = rp[(size_t)c6 * 16 + fl];
        uint2 v7 = rp[(size_t)c7 * 16 + fl];
        s0 += u2h(v0.x); s1 += u2h(v0.y);
        s0 += u2h(v1.x); s1 += u2h(v1.y);
        s0 += u2h(v2.x); s1 += u2h(v2.y);
        s0 += u2h(v3.x); s1 += u2h(v3.y);
        s0 += u2h(v4.x); s1 += u2h(v4.y);
        s0 += u2h(v5.x); s1 += u2h(v5.y);
        s0 += u2h(v6.x); s1 += u2h(v6.y);
        s0 += u2h(v7.x); s1 += u2h(v7.y);
        e += 8;
    }
    if (e + 4 <= en) {
        int c0 = col[e], c1 = col[e + 1], c2 = col[e + 2], c3 = col[e + 3];
        uint2 v0 = rp[(size_t)c0 * 16 + fl];
        uint2 v1 = rp[(size_t)c1 * 16 + fl];
        uint2 v2 = rp[(size_t)c2 * 16 + fl];
        uint2 v3 = rp[(size_t)c3 * 16 + fl];
        s0 += u2h(v0.x); s1 += u2h(v0.y);
        s0 += u2h(v1.x); s1 += u2h(v1.y);
        s0 += u2h(v2.x); s1 += u2h(v2.y);
        s0 += u2h(v3.x); s1 += u2h(v3.y);
        e += 4;
    }
    while (e < en) {
        uint2 v = rp[(size_t)col[e] * 16 + fl];
        s0 += u2h(v.x); s1 += u2h(v.y);
        ++e;
    }
}

// ================= fused gather_k + transform_{k+1} (dot2 path) ===============

__global__ void gt_kernel(const f16* __restrict__ An,
                          const int* __restrict__ rs, const int* __restrict__ re,
                          const int* __restrict__ col, const float* __restrict__ inv,
                          f16* C,
                          const unsigned* __restrict__ Wn16, const float* __restrict__ bn,
                          const unsigned* __restrict__ Wr16,
                          f16* __restrict__ Aout) {
    int lane = threadIdx.x & 63;
    int wid = (blockIdx.x * blockDim.x + threadIdx.x) >> 6;
    int m0 = wid << 2;
    int m = m0 + (lane >> 4);
    int fl = lane & 15;

    f16x2 s0 = (f16x2)0, s1 = (f16x2)0;
    qgather((const uint2*)An, col, rs[m], re[m], fl, s0, s1);

    // h_{k+1}[m] = relu(inv*agg + hrb_k[m]); lane fl holds feats 4fl..4fl+3
    float iv = inv[m];
    uint2 cur = ((const uint2*)C)[(size_t)m * 16 + fl];
    f16x2 q0 = u2h(cur.x), q1 = u2h(cur.y);
    f16x2 hA, hB;
    hA.x = (f16)fmaxf(fmaf((float)s0.x, iv, (float)q0.x), 0.f);
    hA.y = (f16)fmaxf(fmaf((float)s0.y, iv, (float)q0.y), 0.f);
    hB.x = (f16)fmaxf(fmaf((float)s1.x, iv, (float)q1.x), 0.f);
    hB.y = (f16)fmaxf(fmaf((float)s1.y, iv, (float)q1.y), 0.f);
    unsigned hx = h2u(hA), hy = h2u(hB);

    float an[4] = {0.f, 0.f, 0.f, 0.f};
    float ar[4] = {0.f, 0.f, 0.f, 0.f};
#pragma unroll
    for (int kk = 0; kk < 16; ++kk) {
        f16x2 wnA = u2h(Wn16[(2 * kk) * HID + lane]);
        f16x2 wnB = u2h(Wn16[(2 * kk + 1) * HID + lane]);
        f16x2 wrA = u2h(Wr16[(2 * kk) * HID + lane]);
        f16x2 wrB = u2h(Wr16[(2 * kk + 1) * HID + lane]);
#pragma unroll
        for (int n = 0; n < 4; ++n) {
            f16x2 px = u2h(__shfl(hx, (n << 4) + kk));
            f16x2 py = u2h(__shfl(hy, (n << 4) + kk));
            an[n] = dot2(px, wnA, an[n]);
            an[n] = dot2(py, wnB, an[n]);
            ar[n] = dot2(px, wrA, ar[n]);
            ar[n] = dot2(py, wrB, ar[n]);
        }
    }
    float b = bn[lane];
    size_t o = (size_t)m0 * HID + lane;
#pragma unroll
    for (int n = 0; n < 4; ++n) {
        Aout[o + n * HID] = (f16)an[n];
        C[o + n * HID] = (f16)(ar[n] + b);
    }
}

// ================= fused gather_2 (no relu) + predictor head (dot2) ===========

__global__ void gh_kernel(const f16* __restrict__ An,
                          const int* __restrict__ rs, const int* __restrict__ re,
                          const int* __restrict__ col, const float* __restrict__ inv,
                          const f16* __restrict__ C,
                          const unsigned* __restrict__ Wp116, const float* __restrict__ bp1,
                          const float* __restrict__ Wp2, const float* __restrict__ bp2,
                          float* __restrict__ out) {
    int lane = threadIdx.x & 63;
    int wid = (blockIdx.x * blockDim.x + threadIdx.x) >> 6;
    int m0 = wid << 2;
    int m = m0 + (lane >> 4);
    int fl = lane & 15;

    f16x2 s0 = (f16x2)0, s1 = (f16x2)0;
    qgather((const uint2*)An, col, rs[m], re[m], fl, s0, s1);

    float iv = inv[m];
    uint2 cur = ((const uint2*)C)[(size_t)m * 16 + fl];
    f16x2 q0 = u2h(cur.x), q1 = u2h(cur.y);
    f16x2 hA, hB;
    hA.x = (f16)fmaf((float)s0.x, iv, (float)q0.x);
    hA.y = (f16)fmaf((float)s0.y, iv, (float)q0.y);
    hB.x = (f16)fmaf((float)s1.x, iv, (float)q1.x);
    hB.y = (f16)fmaf((float)s1.y, iv, (float)q1.y);
    unsigned hx = h2u(hA), hy = h2u(hB);

    float tn[4] = {0.f, 0.f, 0.f, 0.f};
#pragma unroll
    for (int kk = 0; kk < 16; ++kk) {
        f16x2 wA = u2h(Wp116[(2 * kk) * HID + lane]);
        f16x2 wB = u2h(Wp116[(2 * kk + 1) * HID + lane]);
#pragma unroll
        for (int n = 0; n < 4; ++n) {
            f16x2 px = u2h(__shfl(hx, (n << 4) + kk));
            f16x2 py = u2h(__shfl(hy, (n << 4) + kk));
            tn[n] = dot2(px, wA, tn[n]);
            tn[n] = dot2(py, wB, tn[n]);
        }
    }
    float b = bp1[lane], w2v = Wp2[lane];
    float r0 = fmaxf(tn[0] + b, 0.f) * w2v;
    float r1 = fmaxf(tn[1] + b, 0.f) * w2v;
    float r2 = fmaxf(tn[2] + b, 0.f) * w2v;
    float r3 = fmaxf(tn[3] + b, 0.f) * w2v;
#pragma unroll
    for (int off = 32; off > 0; off >>= 1) {
        r0 += __shfl_xor(r0, off);
        r1 += __shfl_xor(r1, off);
        r2 += __shfl_xor(r2, off);
        r3 += __shfl_xor(r3, off);
    }
    if (lane == 0) {
        float bb = bp2[0];
        out[m0]     = 1.f / (1.f + expf(-(r0 + bb)));
        out[m0 + 1] = 1.f / (1.f + expf(-(r1 + bb)));
        out[m0 + 2] = 1.f / (1.f + expf(-(r2 + bb)));
        out[m0 + 3] = 1.f / (1.f + expf(-(r3 + bb)));
    }
}

extern "C" void kernel_launch(void* const* d_in, const int* in_sizes, int n_in,
                              void* d_out, int out_size, void* d_ws, size_t ws_size,
                              hipStream_t stream) {
    const float* x   = (const float*)d_in[0];
    const int* eidx  = (const int*)d_in[1];
    const float* Wn0 = (const float*)d_in[2];
    const float* bn0 = (const float*)d_in[3];
    const float* Wr0 = (const float*)d_in[4];
    const float* Wn1 = (const float*)d_in[5];
    const float* bn1 = (const float*)d_in[6];
    const float* Wr1 = (const float*)d_in[7];
    const float* Wn2 = (const float*)d_in[8];
    const float* bn2 = (const float*)d_in[9];
    const float* Wr2 = (const float*)d_in[10];
    const float* Wp1 = (const float*)d_in[11];
    const float* bp1 = (const float*)d_in[12];
    const float* Wp2 = (const float*)d_in[13];
    const float* bp2 = (const float*)d_in[14];
    float* out = (float*)d_out;

    const int* src = eidx;
    const int* dst = eidx + EE;

    char* w = (char*)d_ws;
    size_t off = 0;
    auto carve = [&](size_t bytes) -> void* {
        void* p = w + off;
        off = (off + bytes + 255) & ~(size_t)255;
        return p;
    };
    int*   rsA    = (int*)carve((size_t)NN * 4);
    int*   reA    = (int*)carve((size_t)NN * 4);
    float* inv    = (float*)carve((size_t)NN * 4);
    int*   col    = (int*)carve((size_t)BKT * SLAB * 4);   // slab layout
    int*   cnt    = (int*)carve((size_t)NN * 4);
    int*   cursor = (int*)carve((size_t)NN * 4);
    unsigned* w16 = (unsigned*)carve((size_t)5 * 2048 * 4); // packed f16 weights
    f16*   A0     = (f16*)carve((size_t)NN * HID * 2);     // hn ping
    f16*   A1     = (f16*)carve((size_t)NN * HID * 2);     // hn pong
    f16*   C      = (f16*)carve((size_t)NN * HID * 2);     // hrb (own-row in place)
    (void)ws_size;

    unsigned* Wn1_16 = w16;
    unsigned* Wr1_16 = w16 + 2048;
    unsigned* Wn2_16 = w16 + 4096;
    unsigned* Wr2_16 = w16 + 6144;
    unsigned* Wp1_16 = w16 + 8192;

    hipMemsetAsync(cnt, 0, (size_t)NN * 4, stream);

    // K1: per-node degree count || layer-0 transform (+ weight pack)
    ct_kernel<<<NCB + TB, 256, 0, stream>>>(dst, cnt,
                                            x, Wn0, bn0, Wr0, A0, C,
                                            Wn1, Wr1, Wn2, Wr2, Wp1, w16);
    // K2: per-bucket scan -> rs/re/inv/cursor
    scan_kernel<<<BKT, 256, 0, stream>>>(cnt, rsA, reA, inv, cursor);
    // K3: scatter edges into CSR slots
    scat_kernel<<<NCB, 256, 0, stream>>>(src, dst, cursor, col);

    // gather0 + transform1 (reads A0, writes A1 + C)
    gt_kernel<<<TB, 256, 0, stream>>>(A0, rsA, reA, col, inv, C, Wn1_16, bn1, Wr1_16, A1);
    // gather1 + transform2 (reads A1, writes A0 + C)
    gt_kernel<<<TB, 256, 0, stream>>>(A1, rsA, reA, col, inv, C, Wn2_16, bn2, Wr2_16, A0);
    // gather2 + head (reads A0 + C, writes out)
    gh_kernel<<<TB, 256, 0, stream>>>(A0, rsA, reA, col, inv, C, Wp1_16, bp1, Wp2, bp2, out);
}

// Round 4
// 282.130 us; speedup vs baseline: 1.5593x; 1.5593x over previous
//
#include <hip/hip_runtime.h>
#include <math.h>

#define NN 100000
#define EE 1600000
#define HID 64
#define BKT 391                 // ceil(NN/256) buckets of 256 nodes
#define SLAB 5504               // slab capacity per bucket (mean ~4092)
#define SLAB_IT ((SLAB + 255) / 256)     // 22 per-thread iterations in build
#define CHUNK 4096              // edges per workgroup in placement pass
#define NWG ((EE + CHUNK - 1) / CHUNK)   // 391
#define TB (NN / 16)            // 6250 transform blocks (4 waves x 4 nodes)

typedef _Float16 f16;
typedef _Float16 f16x2 __attribute__((ext_vector_type(2)));

__device__ __forceinline__ f16x2 u2h(unsigned u) { return __builtin_bit_cast(f16x2, u); }
__device__ __forceinline__ unsigned h2u(f16x2 h) { return __builtin_bit_cast(unsigned, h); }

#if defined(__has_builtin) && __has_builtin(__builtin_amdgcn_fdot2)
__device__ __forceinline__ float dot2(f16x2 a, f16x2 b, float c) {
    return __builtin_amdgcn_fdot2(a, b, c, false);
}
#else
__device__ __forceinline__ float dot2(f16x2 a, f16x2 b, float c) {
    c = fmaf((float)a.x, (float)b.x, c);
    return fmaf((float)a.y, (float)b.y, c);
}
#endif

// ================= merged: CSR placement (blocks 0..NWG-1) ====================
// ================= || layer-0 transform + weight pack (blocks NWG..) ==========
// r17: rank captured from the counting atomicAdd's return value -> second
// histogram pass + lc reset deleted. Write pattern (bucketized contiguous
// slab runs) unchanged -- r16 proved random scatter costs >100us; never again.

__global__ void mt_kernel(const int* __restrict__ src, const int* __restrict__ dst,
                          int* __restrict__ bfill, unsigned* __restrict__ pairs,
                          const float* __restrict__ h,
                          const float* __restrict__ Wn, const float* __restrict__ bn,
                          const float* __restrict__ Wr,
                          f16* __restrict__ hn, f16* __restrict__ hrb,
                          const float* __restrict__ Wn1, const float* __restrict__ Wr1,
                          const float* __restrict__ Wn2, const float* __restrict__ Wr2,
                          const float* __restrict__ Wp1, unsigned* __restrict__ w16) {
    __shared__ int lc[BKT];
    __shared__ int lbase[BKT];
    int t = threadIdx.x;

    if (blockIdx.x < NWG) {
        // ---- CSR placement ----
        for (int b = t; b < BKT; b += 256) lc[b] = 0;
        __syncthreads();
        int base = blockIdx.x * CHUNK;
        int myd[CHUNK / 256];
        int myr[CHUNK / 256];
#pragma unroll
        for (int j = 0; j < CHUNK / 256; ++j) {
            int i = base + j * 256 + t;
            myd[j] = (i < EE) ? dst[i] : -1;
            myr[j] = (myd[j] >= 0) ? atomicAdd(&lc[myd[j] >> 8], 1) : 0;
        }
        __syncthreads();
        for (int b = t; b < BKT; b += 256) {
            int c = lc[b];
            if (c) {
                int ofs = atomicAdd(&bfill[b], c);
                if (ofs + c > SLAB) ofs = SLAB - c;   // statistically unreachable
                lbase[b] = b * SLAB + ofs;
            }
        }
        __syncthreads();
#pragma unroll
        for (int j = 0; j < CHUNK / 256; ++j) {
            int i = base + j * 256 + t;
            if (myd[j] >= 0) {
                int b = myd[j] >> 8;
                pairs[lbase[b] + myr[j]] = (unsigned)src[i] | ((unsigned)(myd[j] & 255) << 24);
            }
        }
        return;
    }

    int bb = blockIdx.x - NWG;

    // ---- f16 weight pack (first 40 transform blocks) ----
    if (bb < 40) {
        int id = bb * 256 + t;
        int mat = id >> 11;            // 0..4
        int p = (id >> 6) & 31;        // pair index
        int j = id & 63;               // output column
        const float* W = (mat == 0) ? Wn1 : (mat == 1) ? Wr1 :
                         (mat == 2) ? Wn2 : (mat == 3) ? Wr2 : Wp1;
        f16x2 v;
        v.x = (f16)W[(2 * p) * HID + j];
        v.y = (f16)W[(2 * p + 1) * HID + j];
        w16[id] = h2u(v);
    }

    // ---- layer-0 transform: 4 nodes/wave, lane = output column ----
    int lane = t & 63;
    int wid = (bb * 256 + t) >> 6;
    int m0 = __builtin_amdgcn_readfirstlane(wid << 2);
    const float* h0 = h + (size_t)m0 * 32;

    float an0 = 0.f, an1 = 0.f, an2 = 0.f, an3 = 0.f;
    float ar0 = 0.f, ar1 = 0.f, ar2 = 0.f, ar3 = 0.f;
#pragma unroll
    for (int k = 0; k < 32; ++k) {
        float wn = Wn[k * HID + lane];
        float wr = Wr[k * HID + lane];
        float hk0 = h0[k], hk1 = h0[32 + k], hk2 = h0[64 + k], hk3 = h0[96 + k];
        an0 = fmaf(hk0, wn, an0); ar0 = fmaf(hk0, wr, ar0);
        an1 = fmaf(hk1, wn, an1); ar1 = fmaf(hk1, wr, ar1);
        an2 = fmaf(hk2, wn, an2); ar2 = fmaf(hk2, wr, ar2);
        an3 = fmaf(hk3, wn, an3); ar3 = fmaf(hk3, wr, ar3);
    }
    float b = bn[lane];
    size_t o = (size_t)m0 * HID + lane;
    hn[o] = (f16)an0; hn[o + HID] = (f16)an1;
    hn[o + 2 * HID] = (f16)an2; hn[o + 3 * HID] = (f16)an3;
    hrb[o] = (f16)(ar0 + b); hrb[o + HID] = (f16)(ar1 + b);
    hrb[o + 2 * HID] = (f16)(ar2 + b); hrb[o + 3 * HID] = (f16)(ar3 + b);
}

// ================= per-bucket counting sort =================
// r17: pairs read once into registers (fully-unrolled, compile-time indices);
// rank taken from the counting atomic's return value; scatter straight from
// registers. Deletes s_pk[5504] LDS staging (22KB -> 2KB), its re-read, and
// the second histogram pass. col write pattern unchanged.

__global__ void build_kernel(const unsigned* __restrict__ pairs,
                             const int* __restrict__ bfill,
                             int* __restrict__ rs, int* __restrict__ re,
                             float* __restrict__ inv, int* __restrict__ col) {
    __shared__ int ncnt[256];
    __shared__ int nexcl[256];
    int b = blockIdx.x;
    int t = threadIdx.x;
    int s0 = b * SLAB;
    int ce = bfill[b]; if (ce > SLAB) ce = SLAB;
    ncnt[t] = 0;
    __syncthreads();
    unsigned mypk[SLAB_IT];
    int myr[SLAB_IT];
#pragma unroll
    for (int j = 0; j < SLAB_IT; ++j) {
        int e = j * 256 + t;
        if (e < ce) {
            unsigned pk = pairs[s0 + e];
            mypk[j] = pk;
            myr[j] = atomicAdd(&ncnt[pk >> 24], 1);
        }
    }
    __syncthreads();
    int c = ncnt[t];
    nexcl[t] = c;
    __syncthreads();
    for (int off = 1; off < 256; off <<= 1) {
        int u = (t >= off) ? nexcl[t - off] : 0;
        __syncthreads();
        nexcl[t] += u;
        __syncthreads();
    }
    int excl = nexcl[t] - c;
    int node = (b << 8) + t;
    if (node < NN) {
        rs[node] = s0 + excl;
        re[node] = s0 + excl + c;
        inv[node] = (c > 0) ? (1.0f / (float)c) : 0.0f;
    }
    __syncthreads();
    ncnt[t] = excl;          // repurpose: per-key exclusive base for scatter
    __syncthreads();
#pragma unroll
    for (int j = 0; j < SLAB_IT; ++j) {
        int e = j * 256 + t;
        if (e < ce) {
            unsigned pk = mypk[j];
            col[s0 + ncnt[pk >> 24] + myr[j]] = (int)(pk & 0xFFFFFFu);
        }
    }
}

// ================= quarter-wave gather (device helper) =================
// Wave = 4 nodes: lane = (node quarter)<<4 | fl. Each lane loads uint2 (4 f16)
// of a neighbor row; 8-deep main loop (best measured, r12). Packed-f16
// accumulation (accuracy verified r13). KEEP EXACTLY: r14 (shfl 16-deep,
// +10%) and r15 (LDS col stage, +5%) both refuted the col-chain theory --
// gather is MSHR-x-latency bound (~60 lines in flight/CU at ~600cy L3
// latency); source-level load reordering cannot move that ceiling.

__device__ __forceinline__ void qgather(const uint2* __restrict__ rp,
                                        const int* __restrict__ col,
                                        int e, int en, int fl,
                                        f16x2& s0, f16x2& s1) {
    while (e + 8 <= en) {
        int c0 = col[e],     c1 = col[e + 1], c2 = col[e + 2], c3 = col[e + 3];
        int c4 = col[e + 4], c5 = col[e + 5], c6 = col[e + 6], c7 = col[e + 7];
        uint2 v0 = rp[(size_t)c0 * 16 + fl];
        uint2 v1 = rp[(size_t)c1 * 16 + fl];
        uint2 v2 = rp[(size_t)c2 * 16 + fl];
        uint2 v3 = rp[(size_t)c3 * 16 + fl];
        uint2 v4 = rp[(size_t)c4 * 16 + fl];
        uint2 v5 = rp[(size_t)c5 * 16 + fl];
        uint2 v6 = rp[(size_t)c6 * 16 + fl];
        uint2 v7 = rp[(size_t)c7 * 16 + fl];
        s0 += u2h(v0.x); s1 += u2h(v0.y);
        s0 += u2h(v1.x); s1 += u2h(v1.y);
        s0 += u2h(v2.x); s1 += u2h(v2.y);
        s0 += u2h(v3.x); s1 += u2h(v3.y);
        s0 += u2h(v4.x); s1 += u2h(v4.y);
        s0 += u2h(v5.x); s1 += u2h(v5.y);
        s0 += u2h(v6.x); s1 += u2h(v6.y);
        s0 += u2h(v7.x); s1 += u2h(v7.y);
        e += 8;
    }
    if (e + 4 <= en) {
        int c0 = col[e], c1 = col[e + 1], c2 = col[e + 2], c3 = col[e + 3];
        uint2 v0 = rp[(size_t)c0 * 16 + fl];
        uint2 v1 = rp[(size_t)c1 * 16 + fl];
        uint2 v2 = rp[(size_t)c2 * 16 + fl];
        uint2 v3 = rp[(size_t)c3 * 16 + fl];
        s0 += u2h(v0.x); s1 += u2h(v0.y);
        s0 += u2h(v1.x); s1 += u2h(v1.y);
        s0 += u2h(v2.x); s1 += u2h(v2.y);
        s0 += u2h(v3.x); s1 += u2h(v3.y);
        e += 4;
    }
    while (e < en) {
        uint2 v = rp[(size_t)col[e] * 16 + fl];
        s0 += u2h(v.x); s1 += u2h(v.y);
        ++e;
    }
}

// ================= fused gather_k + transform_{k+1} (dot2 path) ===============

__global__ void gt_kernel(const f16* __restrict__ An,
                          const int* __restrict__ rs, const int* __restrict__ re,
                          const int* __restrict__ col, const float* __restrict__ inv,
                          f16* C,
                          const unsigned* __restrict__ Wn16, const float* __restrict__ bn,
                          const unsigned* __restrict__ Wr16,
                          f16* __restrict__ Aout) {
    int lane = threadIdx.x & 63;
    int wid = (blockIdx.x * blockDim.x + threadIdx.x) >> 6;
    int m0 = wid << 2;
    int m = m0 + (lane >> 4);
    int fl = lane & 15;

    f16x2 s0 = (f16x2)0, s1 = (f16x2)0;
    qgather((const uint2*)An, col, rs[m], re[m], fl, s0, s1);

    // h_{k+1}[m] = relu(inv*agg + hrb_k[m]); lane fl holds feats 4fl..4fl+3
    float iv = inv[m];
    uint2 cur = ((const uint2*)C)[(size_t)m * 16 + fl];
    f16x2 q0 = u2h(cur.x), q1 = u2h(cur.y);
    f16x2 hA, hB;
    hA.x = (f16)fmaxf(fmaf((float)s0.x, iv, (float)q0.x), 0.f);
    hA.y = (f16)fmaxf(fmaf((float)s0.y, iv, (float)q0.y), 0.f);
    hB.x = (f16)fmaxf(fmaf((float)s1.x, iv, (float)q1.x), 0.f);
    hB.y = (f16)fmaxf(fmaf((float)s1.y, iv, (float)q1.y), 0.f);
    unsigned hx = h2u(hA), hy = h2u(hB);

    float an[4] = {0.f, 0.f, 0.f, 0.f};
    float ar[4] = {0.f, 0.f, 0.f, 0.f};
#pragma unroll
    for (int kk = 0; kk < 16; ++kk) {
        f16x2 wnA = u2h(Wn16[(2 * kk) * HID + lane]);
        f16x2 wnB = u2h(Wn16[(2 * kk + 1) * HID + lane]);
        f16x2 wrA = u2h(Wr16[(2 * kk) * HID + lane]);
        f16x2 wrB = u2h(Wr16[(2 * kk + 1) * HID + lane]);
#pragma unroll
        for (int n = 0; n < 4; ++n) {
            f16x2 px = u2h(__shfl(hx, (n << 4) + kk));
            f16x2 py = u2h(__shfl(hy, (n << 4) + kk));
            an[n] = dot2(px, wnA, an[n]);
            an[n] = dot2(py, wnB, an[n]);
            ar[n] = dot2(px, wrA, ar[n]);
            ar[n] = dot2(py, wrB, ar[n]);
        }
    }
    float b = bn[lane];
    size_t o = (size_t)m0 * HID + lane;
#pragma unroll
    for (int n = 0; n < 4; ++n) {
        Aout[o + n * HID] = (f16)an[n];
        C[o + n * HID] = (f16)(ar[n] + b);
    }
}

// ================= fused gather_2 (no relu) + predictor head (dot2) ===========

__global__ void gh_kernel(const f16* __restrict__ An,
                          const int* __restrict__ rs, const int* __restrict__ re,
                          const int* __restrict__ col, const float* __restrict__ inv,
                          const f16* __restrict__ C,
                          const unsigned* __restrict__ Wp116, const float* __restrict__ bp1,
                          const float* __restrict__ Wp2, const float* __restrict__ bp2,
                          float* __restrict__ out) {
    int lane = threadIdx.x & 63;
    int wid = (blockIdx.x * blockDim.x + threadIdx.x) >> 6;
    int m0 = wid << 2;
    int m = m0 + (lane >> 4);
    int fl = lane & 15;

    f16x2 s0 = (f16x2)0, s1 = (f16x2)0;
    qgather((const uint2*)An, col, rs[m], re[m], fl, s0, s1);

    float iv = inv[m];
    uint2 cur = ((const uint2*)C)[(size_t)m * 16 + fl];
    f16x2 q0 = u2h(cur.x), q1 = u2h(cur.y);
    f16x2 hA, hB;
    hA.x = (f16)fmaf((float)s0.x, iv, (float)q0.x);
    hA.y = (f16)fmaf((float)s0.y, iv, (float)q0.y);
    hB.x = (f16)fmaf((float)s1.x, iv, (float)q1.x);
    hB.y = (f16)fmaf((float)s1.y, iv, (float)q1.y);
    unsigned hx = h2u(hA), hy = h2u(hB);

    float tn[4] = {0.f, 0.f, 0.f, 0.f};
#pragma unroll
    for (int kk = 0; kk < 16; ++kk) {
        f16x2 wA = u2h(Wp116[(2 * kk) * HID + lane]);
        f16x2 wB = u2h(Wp116[(2 * kk + 1) * HID + lane]);
#pragma unroll
        for (int n = 0; n < 4; ++n) {
            f16x2 px = u2h(__shfl(hx, (n << 4) + kk));
            f16x2 py = u2h(__shfl(hy, (n << 4) + kk));
            tn[n] = dot2(px, wA, tn[n]);
            tn[n] = dot2(py, wB, tn[n]);
        }
    }
    float b = bp1[lane], w2v = Wp2[lane];
    float r0 = fmaxf(tn[0] + b, 0.f) * w2v;
    float r1 = fmaxf(tn[1] + b, 0.f) * w2v;
    float r2 = fmaxf(tn[2] + b, 0.f) * w2v;
    float r3 = fmaxf(tn[3] + b, 0.f) * w2v;
#pragma unroll
    for (int off = 32; off > 0; off >>= 1) {
        r0 += __shfl_xor(r0, off);
        r1 += __shfl_xor(r1, off);
        r2 += __shfl_xor(r2, off);
        r3 += __shfl_xor(r3, off);
    }
    if (lane == 0) {
        float bb = bp2[0];
        out[m0]     = 1.f / (1.f + expf(-(r0 + bb)));
        out[m0 + 1] = 1.f / (1.f + expf(-(r1 + bb)));
        out[m0 + 2] = 1.f / (1.f + expf(-(r2 + bb)));
        out[m0 + 3] = 1.f / (1.f + expf(-(r3 + bb)));
    }
}

extern "C" void kernel_launch(void* const* d_in, const int* in_sizes, int n_in,
                              void* d_out, int out_size, void* d_ws, size_t ws_size,
                              hipStream_t stream) {
    const float* x   = (const float*)d_in[0];
    const int* eidx  = (const int*)d_in[1];
    const float* Wn0 = (const float*)d_in[2];
    const float* bn0 = (const float*)d_in[3];
    const float* Wr0 = (const float*)d_in[4];
    const float* Wn1 = (const float*)d_in[5];
    const float* bn1 = (const float*)d_in[6];
    const float* Wr1 = (const float*)d_in[7];
    const float* Wn2 = (const float*)d_in[8];
    const float* bn2 = (const float*)d_in[9];
    const float* Wr2 = (const float*)d_in[10];
    const float* Wp1 = (const float*)d_in[11];
    const float* bp1 = (const float*)d_in[12];
    const float* Wp2 = (const float*)d_in[13];
    const float* bp2 = (const float*)d_in[14];
    float* out = (float*)d_out;

    const int* src = eidx;
    const int* dst = eidx + EE;

    char* w = (char*)d_ws;
    size_t off = 0;
    auto carve = [&](size_t bytes) -> void* {
        void* p = w + off;
        off = (off + bytes + 255) & ~(size_t)255;
        return p;
    };
    int*   rsA    = (int*)carve((size_t)NN * 4);
    int*   reA    = (int*)carve((size_t)NN * 4);
    float* inv    = (float*)carve((size_t)NN * 4);
    int*   col    = (int*)carve((size_t)BKT * SLAB * 4);   // slab layout
    int*   bfill  = (int*)carve((size_t)BKT * 4);
    unsigned* w16 = (unsigned*)carve((size_t)5 * 2048 * 4); // packed f16 weights
    f16*   A0     = (f16*)carve((size_t)NN * HID * 2);     // hn ping
    f16*   A1     = (f16*)carve((size_t)NN * HID * 2);     // hn pong
    f16*   C      = (f16*)carve((size_t)NN * HID * 2);     // hrb (own-row in place)
    unsigned* pairs = (unsigned*)carve((size_t)BKT * SLAB * 4);
    (void)ws_size;

    unsigned* Wn1_16 = w16;
    unsigned* Wr1_16 = w16 + 2048;
    unsigned* Wn2_16 = w16 + 4096;
    unsigned* Wr2_16 = w16 + 6144;
    unsigned* Wp1_16 = w16 + 8192;

    hipMemsetAsync(bfill, 0, (size_t)BKT * 4, stream);

    // merged: CSR placement || layer-0 transform (+ weight pack)
    mt_kernel<<<NWG + TB, 256, 0, stream>>>(src, dst, bfill, pairs,
                                            x, Wn0, bn0, Wr0, A0, C,
                                            Wn1, Wr1, Wn2, Wr2, Wp1, w16);
    // per-bucket counting sort
    build_kernel<<<BKT, 256, 0, stream>>>(pairs, bfill, rsA, reA, inv, col);

    // gather0 + transform1 (reads A0, writes A1 + C)
    gt_kernel<<<TB, 256, 0, stream>>>(A0, rsA, reA, col, inv, C, Wn1_16, bn1, Wr1_16, A1);
    // gather1 + transform2 (reads A1, writes A0 + C)
    gt_kernel<<<TB, 256, 0, stream>>>(A1, rsA, reA, col, inv, C, Wn2_16, bn2, Wr2_16, A0);
    // gather2 + head (reads A0 + C, writes out)
    gh_kernel<<<TB, 256, 0, stream>>>(A0, rsA, reA, col, inv, C, Wp1_16, bp1, Wp2, bp2, out);
}

// Round 5
// 274.589 us; speedup vs baseline: 1.6021x; 1.0275x over previous
//
#include <hip/hip_runtime.h>
#include <math.h>

#define NN 100000
#define EE 1600000
#define HID 64
#define BKT 391                 // ceil(NN/256) buckets of 256 nodes
#define SLAB 5504               // slab capacity per bucket (mean ~4092)
#define SLAB_IT ((SLAB + 255) / 256)     // 22 per-thread iterations in build
#define CHUNK 4096              // edges per workgroup in placement pass
#define NWG ((EE + CHUNK - 1) / CHUNK)   // 391
#define TB (NN / 16)            // 6250 transform blocks (4 waves x 4 nodes)

typedef _Float16 f16;
typedef _Float16 f16x2 __attribute__((ext_vector_type(2)));

__device__ __forceinline__ f16x2 u2h(unsigned u) { return __builtin_bit_cast(f16x2, u); }
__device__ __forceinline__ unsigned h2u(f16x2 h) { return __builtin_bit_cast(unsigned, h); }

#if defined(__has_builtin) && __has_builtin(__builtin_amdgcn_fdot2)
__device__ __forceinline__ float dot2(f16x2 a, f16x2 b, float c) {
    return __builtin_amdgcn_fdot2(a, b, c, false);
}
#else
__device__ __forceinline__ float dot2(f16x2 a, f16x2 b, float c) {
    c = fmaf((float)a.x, (float)b.x, c);
    return fmaf((float)a.y, (float)b.y, c);
}
#endif

// ===================== fp8 (OCP e4m3) helpers =================================
// r18: An rows stored as e4m3 -> 64B/row = ONE cache line per neighbor read
// (was 2). Gather is line-count x latency bound (r14/r15/r17 nulls); halving
// lines is the only remaining lever. Accumulation upgraded f16 -> f32.

#if defined(__has_builtin)
#if __has_builtin(__builtin_amdgcn_cvt_pk_f32_fp8) && __has_builtin(__builtin_amdgcn_cvt_pk_fp8_f32)
#define HW_FP8 1
#endif
#endif

#ifndef HW_FP8
__device__ __forceinline__ float dec_e4m3(unsigned b) {
    unsigned s = b >> 7, e = (b >> 3) & 0xF, m = b & 7;
    float v;
    if (e == 0) v = (float)m * 0.001953125f;                 // m * 2^-9
    else v = (1.f + (float)m * 0.125f) * exp2f((float)((int)e - 7));
    return s ? -v : v;
}
__device__ __forceinline__ unsigned char enc_e4m3(float x) {
    unsigned s = (__builtin_bit_cast(unsigned, x) >> 31) << 7;
    float a = fabsf(x);
    if (!(a < 464.f)) return (unsigned char)(s | 0x7E);      // clamp / NaN->max
    int e; float m = frexpf(a, &e);                          // a = m*2^e, m in [0.5,1)
    int E = e - 1;
    unsigned bits;
    if (E < -6) {
        int n = (int)rintf(a * 512.f);
        bits = (n > 7) ? 0x08u : (unsigned)n;
    } else {
        int n = (int)rintf((2.f * m - 1.f) * 8.f);
        if (n == 8) { n = 0; E += 1; }
        if (E > 8) return (unsigned char)(s | 0x7E);
        bits = ((unsigned)(E + 7) << 3) | (unsigned)n;
    }
    return (unsigned char)(s | bits);
}
#endif

__device__ __forceinline__ void acc_fp8(unsigned v, float& a0, float& a1,
                                        float& a2, float& a3) {
#ifdef HW_FP8
    auto lo = __builtin_amdgcn_cvt_pk_f32_fp8((int)v, false);
    auto hi = __builtin_amdgcn_cvt_pk_f32_fp8((int)v, true);
    a0 += lo[0]; a1 += lo[1]; a2 += hi[0]; a3 += hi[1];
#else
    a0 += dec_e4m3(v & 0xFFu);         a1 += dec_e4m3((v >> 8) & 0xFFu);
    a2 += dec_e4m3((v >> 16) & 0xFFu); a3 += dec_e4m3(v >> 24);
#endif
}

__device__ __forceinline__ unsigned char enc_fp8(float x) {
#ifdef HW_FP8
    return (unsigned char)(__builtin_amdgcn_cvt_pk_fp8_f32(x, x, 0, false) & 0xFF);
#else
    return enc_e4m3(x);
#endif
}

// ================= merged: CSR placement (blocks 0..NWG-1) ====================
// ================= || layer-0 transform + weight pack (blocks NWG..) ==========
// r17: rank captured from the counting atomicAdd's return value. Write pattern
// (bucketized contiguous slab runs) unchanged -- r16 proved random scatter
// costs >100us; never again.

__global__ void mt_kernel(const int* __restrict__ src, const int* __restrict__ dst,
                          int* __restrict__ bfill, unsigned* __restrict__ pairs,
                          const float* __restrict__ h,
                          const float* __restrict__ Wn, const float* __restrict__ bn,
                          const float* __restrict__ Wr,
                          unsigned char* __restrict__ hn8, f16* __restrict__ hrb,
                          const float* __restrict__ Wn1, const float* __restrict__ Wr1,
                          const float* __restrict__ Wn2, const float* __restrict__ Wr2,
                          const float* __restrict__ Wp1, unsigned* __restrict__ w16) {
    __shared__ int lc[BKT];
    __shared__ int lbase[BKT];
    int t = threadIdx.x;

    if (blockIdx.x < NWG) {
        // ---- CSR placement ----
        for (int b = t; b < BKT; b += 256) lc[b] = 0;
        __syncthreads();
        int base = blockIdx.x * CHUNK;
        int myd[CHUNK / 256];
        int myr[CHUNK / 256];
#pragma unroll
        for (int j = 0; j < CHUNK / 256; ++j) {
            int i = base + j * 256 + t;
            myd[j] = (i < EE) ? dst[i] : -1;
            myr[j] = (myd[j] >= 0) ? atomicAdd(&lc[myd[j] >> 8], 1) : 0;
        }
        __syncthreads();
        for (int b = t; b < BKT; b += 256) {
            int c = lc[b];
            if (c) {
                int ofs = atomicAdd(&bfill[b], c);
                if (ofs + c > SLAB) ofs = SLAB - c;   // statistically unreachable
                lbase[b] = b * SLAB + ofs;
            }
        }
        __syncthreads();
#pragma unroll
        for (int j = 0; j < CHUNK / 256; ++j) {
            int i = base + j * 256 + t;
            if (myd[j] >= 0) {
                int b = myd[j] >> 8;
                pairs[lbase[b] + myr[j]] = (unsigned)src[i] | ((unsigned)(myd[j] & 255) << 24);
            }
        }
        return;
    }

    int bb = blockIdx.x - NWG;

    // ---- f16 weight pack (first 40 transform blocks) ----
    if (bb < 40) {
        int id = bb * 256 + t;
        int mat = id >> 11;            // 0..4
        int p = (id >> 6) & 31;        // pair index
        int j = id & 63;               // output column
        const float* W = (mat == 0) ? Wn1 : (mat == 1) ? Wr1 :
                         (mat == 2) ? Wn2 : (mat == 3) ? Wr2 : Wp1;
        f16x2 v;
        v.x = (f16)W[(2 * p) * HID + j];
        v.y = (f16)W[(2 * p + 1) * HID + j];
        w16[id] = h2u(v);
    }

    // ---- layer-0 transform: 4 nodes/wave, lane = output column ----
    int lane = t & 63;
    int wid = (bb * 256 + t) >> 6;
    int m0 = __builtin_amdgcn_readfirstlane(wid << 2);
    const float* h0 = h + (size_t)m0 * 32;

    float an0 = 0.f, an1 = 0.f, an2 = 0.f, an3 = 0.f;
    float ar0 = 0.f, ar1 = 0.f, ar2 = 0.f, ar3 = 0.f;
#pragma unroll
    for (int k = 0; k < 32; ++k) {
        float wn = Wn[k * HID + lane];
        float wr = Wr[k * HID + lane];
        float hk0 = h0[k], hk1 = h0[32 + k], hk2 = h0[64 + k], hk3 = h0[96 + k];
        an0 = fmaf(hk0, wn, an0); ar0 = fmaf(hk0, wr, ar0);
        an1 = fmaf(hk1, wn, an1); ar1 = fmaf(hk1, wr, ar1);
        an2 = fmaf(hk2, wn, an2); ar2 = fmaf(hk2, wr, ar2);
        an3 = fmaf(hk3, wn, an3); ar3 = fmaf(hk3, wr, ar3);
    }
    float b = bn[lane];
    size_t o8 = (size_t)m0 * HID + lane;        // fp8: 1 byte per feature
    hn8[o8] = enc_fp8(an0);
    hn8[o8 + HID] = enc_fp8(an1);
    hn8[o8 + 2 * HID] = enc_fp8(an2);
    hn8[o8 + 3 * HID] = enc_fp8(an3);
    size_t o = (size_t)m0 * HID + lane;
    hrb[o] = (f16)(ar0 + b); hrb[o + HID] = (f16)(ar1 + b);
    hrb[o + 2 * HID] = (f16)(ar2 + b); hrb[o + 3 * HID] = (f16)(ar3 + b);
}

// ================= per-bucket counting sort (r17 register form) ===============

__global__ void build_kernel(const unsigned* __restrict__ pairs,
                             const int* __restrict__ bfill,
                             int* __restrict__ rs, int* __restrict__ re,
                             float* __restrict__ inv, int* __restrict__ col) {
    __shared__ int ncnt[256];
    __shared__ int nexcl[256];
    int b = blockIdx.x;
    int t = threadIdx.x;
    int s0 = b * SLAB;
    int ce = bfill[b]; if (ce > SLAB) ce = SLAB;
    ncnt[t] = 0;
    __syncthreads();
    unsigned mypk[SLAB_IT];
    int myr[SLAB_IT];
#pragma unroll
    for (int j = 0; j < SLAB_IT; ++j) {
        int e = j * 256 + t;
        if (e < ce) {
            unsigned pk = pairs[s0 + e];
            mypk[j] = pk;
            myr[j] = atomicAdd(&ncnt[pk >> 24], 1);
        }
    }
    __syncthreads();
    int c = ncnt[t];
    nexcl[t] = c;
    __syncthreads();
    for (int off = 1; off < 256; off <<= 1) {
        int u = (t >= off) ? nexcl[t - off] : 0;
        __syncthreads();
        nexcl[t] += u;
        __syncthreads();
    }
    int excl = nexcl[t] - c;
    int node = (b << 8) + t;
    if (node < NN) {
        rs[node] = s0 + excl;
        re[node] = s0 + excl + c;
        inv[node] = (c > 0) ? (1.0f / (float)c) : 0.0f;
    }
    __syncthreads();
    ncnt[t] = excl;          // repurpose: per-key exclusive base for scatter
    __syncthreads();
#pragma unroll
    for (int j = 0; j < SLAB_IT; ++j) {
        int e = j * 256 + t;
        if (e < ce) {
            unsigned pk = mypk[j];
            col[s0 + ncnt[pk >> 24] + myr[j]] = (int)(pk & 0xFFFFFFu);
        }
    }
}

// ================= quarter-wave gather, fp8 rows (device helper) ==============
// Wave = 4 nodes: lane = (node quarter)<<4 | fl. Each lane loads 1 dword
// (4 e4m3) of a neighbor row; row = 64B = ONE line. 8-deep main loop (best
// measured r12); f32 accumulation. KEEP STRUCTURE: r14 (shfl 16-deep, +10%)
// and r15 (LDS col stage, +5%) refuted ILP restructuring -- gather is
// line-count x latency bound; fp8 halves the line count.

__device__ __forceinline__ void qgather8(const unsigned* __restrict__ rp,
                                         const int* __restrict__ col,
                                         int e, int en, int fl,
                                         float& a0, float& a1, float& a2, float& a3) {
    while (e + 8 <= en) {
        int c0 = col[e],     c1 = col[e + 1], c2 = col[e + 2], c3 = col[e + 3];
        int c4 = col[e + 4], c5 = col[e + 5], c6 = col[e + 6], c7 = col[e + 7];
        unsigned v0 = rp[(size_t)c0 * 16 + fl];
        unsigned v1 = rp[(size_t)c1 * 16 + fl];
        unsigned v2 = rp[(size_t)c2 * 16 + fl];
        unsigned v3 = rp[(size_t)c3 * 16 + fl];
        unsigned v4 = rp[(size_t)c4 * 16 + fl];
        unsigned v5 = rp[(size_t)c5 * 16 + fl];
        unsigned v6 = rp[(size_t)c6 * 16 + fl];
        unsigned v7 = rp[(size_t)c7 * 16 + fl];
        acc_fp8(v0, a0, a1, a2, a3);
        acc_fp8(v1, a0, a1, a2, a3);
        acc_fp8(v2, a0, a1, a2, a3);
        acc_fp8(v3, a0, a1, a2, a3);
        acc_fp8(v4, a0, a1, a2, a3);
        acc_fp8(v5, a0, a1, a2, a3);
        acc_fp8(v6, a0, a1, a2, a3);
        acc_fp8(v7, a0, a1, a2, a3);
        e += 8;
    }
    if (e + 4 <= en) {
        int c0 = col[e], c1 = col[e + 1], c2 = col[e + 2], c3 = col[e + 3];
        unsigned v0 = rp[(size_t)c0 * 16 + fl];
        unsigned v1 = rp[(size_t)c1 * 16 + fl];
        unsigned v2 = rp[(size_t)c2 * 16 + fl];
        unsigned v3 = rp[(size_t)c3 * 16 + fl];
        acc_fp8(v0, a0, a1, a2, a3);
        acc_fp8(v1, a0, a1, a2, a3);
        acc_fp8(v2, a0, a1, a2, a3);
        acc_fp8(v3, a0, a1, a2, a3);
        e += 4;
    }
    while (e < en) {
        unsigned v = rp[(size_t)col[e] * 16 + fl];
        acc_fp8(v, a0, a1, a2, a3);
        ++e;
    }
}

// ================= fused gather_k + transform_{k+1} (dot2 path) ===============

__global__ void gt_kernel(const unsigned char* __restrict__ An8,
                          const int* __restrict__ rs, const int* __restrict__ re,
                          const int* __restrict__ col, const float* __restrict__ inv,
                          f16* C,
                          const unsigned* __restrict__ Wn16, const float* __restrict__ bn,
                          const unsigned* __restrict__ Wr16,
                          unsigned char* __restrict__ Aout8) {
    int lane = threadIdx.x & 63;
    int wid = (blockIdx.x * blockDim.x + threadIdx.x) >> 6;
    int m0 = wid << 2;
    int m = m0 + (lane >> 4);
    int fl = lane & 15;

    float a0 = 0.f, a1 = 0.f, a2 = 0.f, a3 = 0.f;
    qgather8((const unsigned*)An8, col, rs[m], re[m], fl, a0, a1, a2, a3);

    // h_{k+1}[m] = relu(inv*agg + hrb_k[m]); lane fl holds feats 4fl..4fl+3
    float iv = inv[m];
    uint2 cur = ((const uint2*)C)[(size_t)m * 16 + fl];
    f16x2 q0 = u2h(cur.x), q1 = u2h(cur.y);
    f16x2 hA, hB;
    hA.x = (f16)fmaxf(fmaf(a0, iv, (float)q0.x), 0.f);
    hA.y = (f16)fmaxf(fmaf(a1, iv, (float)q0.y), 0.f);
    hB.x = (f16)fmaxf(fmaf(a2, iv, (float)q1.x), 0.f);
    hB.y = (f16)fmaxf(fmaf(a3, iv, (float)q1.y), 0.f);
    unsigned hx = h2u(hA), hy = h2u(hB);

    float an[4] = {0.f, 0.f, 0.f, 0.f};
    float ar[4] = {0.f, 0.f, 0.f, 0.f};
#pragma unroll
    for (int kk = 0; kk < 16; ++kk) {
        f16x2 wnA = u2h(Wn16[(2 * kk) * HID + lane]);
        f16x2 wnB = u2h(Wn16[(2 * kk + 1) * HID + lane]);
        f16x2 wrA = u2h(Wr16[(2 * kk) * HID + lane]);
        f16x2 wrB = u2h(Wr16[(2 * kk + 1) * HID + lane]);
#pragma unroll
        for (int n = 0; n < 4; ++n) {
            f16x2 px = u2h(__shfl(hx, (n << 4) + kk));
            f16x2 py = u2h(__shfl(hy, (n << 4) + kk));
            an[n] = dot2(px, wnA, an[n]);
            an[n] = dot2(py, wnB, an[n]);
            ar[n] = dot2(px, wrA, ar[n]);
            ar[n] = dot2(py, wrB, ar[n]);
        }
    }
    float b = bn[lane];
    size_t o8 = (size_t)m0 * HID + lane;
    size_t o = (size_t)m0 * HID + lane;
#pragma unroll
    for (int n = 0; n < 4; ++n) {
        Aout8[o8 + n * HID] = enc_fp8(an[n]);
        C[o + n * HID] = (f16)(ar[n] + b);
    }
}

// ================= fused gather_2 (no relu) + predictor head (dot2) ===========

__global__ void gh_kernel(const unsigned char* __restrict__ An8,
                          const int* __restrict__ rs, const int* __restrict__ re,
                          const int* __restrict__ col, const float* __restrict__ inv,
                          const f16* __restrict__ C,
                          const unsigned* __restrict__ Wp116, const float* __restrict__ bp1,
                          const float* __restrict__ Wp2, const float* __restrict__ bp2,
                          float* __restrict__ out) {
    int lane = threadIdx.x & 63;
    int wid = (blockIdx.x * blockDim.x + threadIdx.x) >> 6;
    int m0 = wid << 2;
    int m = m0 + (lane >> 4);
    int fl = lane & 15;

    float a0 = 0.f, a1 = 0.f, a2 = 0.f, a3 = 0.f;
    qgather8((const unsigned*)An8, col, rs[m], re[m], fl, a0, a1, a2, a3);

    float iv = inv[m];
    uint2 cur = ((const uint2*)C)[(size_t)m * 16 + fl];
    f16x2 q0 = u2h(cur.x), q1 = u2h(cur.y);
    f16x2 hA, hB;
    hA.x = (f16)fmaf(a0, iv, (float)q0.x);
    hA.y = (f16)fmaf(a1, iv, (float)q0.y);
    hB.x = (f16)fmaf(a2, iv, (float)q1.x);
    hB.y = (f16)fmaf(a3, iv, (float)q1.y);
    unsigned hx = h2u(hA), hy = h2u(hB);

    float tn[4] = {0.f, 0.f, 0.f, 0.f};
#pragma unroll
    for (int kk = 0; kk < 16; ++kk) {
        f16x2 wA = u2h(Wp116[(2 * kk) * HID + lane]);
        f16x2 wB = u2h(Wp116[(2 * kk + 1) * HID + lane]);
#pragma unroll
        for (int n = 0; n < 4; ++n) {
            f16x2 px = u2h(__shfl(hx, (n << 4) + kk));
            f16x2 py = u2h(__shfl(hy, (n << 4) + kk));
            tn[n] = dot2(px, wA, tn[n]);
            tn[n] = dot2(py, wB, tn[n]);
        }
    }
    float b = bp1[lane], w2v = Wp2[lane];
    float r0 = fmaxf(tn[0] + b, 0.f) * w2v;
    float r1 = fmaxf(tn[1] + b, 0.f) * w2v;
    float r2 = fmaxf(tn[2] + b, 0.f) * w2v;
    float r3 = fmaxf(tn[3] + b, 0.f) * w2v;
#pragma unroll
    for (int off = 32; off > 0; off >>= 1) {
        r0 += __shfl_xor(r0, off);
        r1 += __shfl_xor(r1, off);
        r2 += __shfl_xor(r2, off);
        r3 += __shfl_xor(r3, off);
    }
    if (lane == 0) {
        float bb = bp2[0];
        out[m0]     = 1.f / (1.f + expf(-(r0 + bb)));
        out[m0 + 1] = 1.f / (1.f + expf(-(r1 + bb)));
        out[m0 + 2] = 1.f / (1.f + expf(-(r2 + bb)));
        out[m0 + 3] = 1.f / (1.f + expf(-(r3 + bb)));
    }
}

extern "C" void kernel_launch(void* const* d_in, const int* in_sizes, int n_in,
                              void* d_out, int out_size, void* d_ws, size_t ws_size,
                              hipStream_t stream) {
    const float* x   = (const float*)d_in[0];
    const int* eidx  = (const int*)d_in[1];
    const float* Wn0 = (const float*)d_in[2];
    const float* bn0 = (const float*)d_in[3];
    const float* Wr0 = (const float*)d_in[4];
    const float* Wn1 = (const float*)d_in[5];
    const float* bn1 = (const float*)d_in[6];
    const float* Wr1 = (const float*)d_in[7];
    const float* Wn2 = (const float*)d_in[8];
    const float* bn2 = (const float*)d_in[9];
    const float* Wr2 = (const float*)d_in[10];
    const float* Wp1 = (const float*)d_in[11];
    const float* bp1 = (const float*)d_in[12];
    const float* Wp2 = (const float*)d_in[13];
    const float* bp2 = (const float*)d_in[14];
    float* out = (float*)d_out;

    const int* src = eidx;
    const int* dst = eidx + EE;

    char* w = (char*)d_ws;
    size_t off = 0;
    auto carve = [&](size_t bytes) -> void* {
        void* p = w + off;
        off = (off + bytes + 255) & ~(size_t)255;
        return p;
    };
    int*   rsA    = (int*)carve((size_t)NN * 4);
    int*   reA    = (int*)carve((size_t)NN * 4);
    float* inv    = (float*)carve((size_t)NN * 4);
    int*   col    = (int*)carve((size_t)BKT * SLAB * 4);   // slab layout
    int*   bfill  = (int*)carve((size_t)BKT * 4);
    unsigned* w16 = (unsigned*)carve((size_t)5 * 2048 * 4); // packed f16 weights
    unsigned char* A0 = (unsigned char*)carve((size_t)NN * HID);  // fp8 hn ping (64B rows)
    unsigned char* A1 = (unsigned char*)carve((size_t)NN * HID);  // fp8 hn pong
    f16*   C      = (f16*)carve((size_t)NN * HID * 2);     // hrb f16 (own-row in place)
    unsigned* pairs = (unsigned*)carve((size_t)BKT * SLAB * 4);
    (void)ws_size;

    unsigned* Wn1_16 = w16;
    unsigned* Wr1_16 = w16 + 2048;
    unsigned* Wn2_16 = w16 + 4096;
    unsigned* Wr2_16 = w16 + 6144;
    unsigned* Wp1_16 = w16 + 8192;

    hipMemsetAsync(bfill, 0, (size_t)BKT * 4, stream);

    // merged: CSR placement || layer-0 transform (+ weight pack)
    mt_kernel<<<NWG + TB, 256, 0, stream>>>(src, dst, bfill, pairs,
                                            x, Wn0, bn0, Wr0, A0, C,
                                            Wn1, Wr1, Wn2, Wr2, Wp1, w16);
    // per-bucket counting sort
    build_kernel<<<BKT, 256, 0, stream>>>(pairs, bfill, rsA, reA, inv, col);

    // gather0 + transform1 (reads A0, writes A1 + C)
    gt_kernel<<<TB, 256, 0, stream>>>(A0, rsA, reA, col, inv, C, Wn1_16, bn1, Wr1_16, A1);
    // gather1 + transform2 (reads A1, writes A0 + C)
    gt_kernel<<<TB, 256, 0, stream>>>(A1, rsA, reA, col, inv, C, Wn2_16, bn2, Wr2_16, A0);
    // gather2 + head (reads A0 + C, writes out)
    gh_kernel<<<TB, 256, 0, stream>>>(A0, rsA, reA, col, inv, C, Wp1_16, bp1, Wp2, bp2, out);
}

// Round 6
// 244.225 us; speedup vs baseline: 1.8013x; 1.1243x over previous
//
#include <hip/hip_runtime.h>
#include <math.h>

#define NN 100000
#define EE 1600000
#define HID 64
#define BKT 391                 // ceil(NN/256) buckets of 256 nodes
#define SLAB 5504               // slab capacity per bucket (mean true ~4092, padded ~4476)
#define SLAB_IT ((SLAB + 255) / 256)     // 22 per-thread iterations in build
#define CHUNK 4096              // edges per workgroup in placement pass
#define NWG ((EE + CHUNK - 1) / CHUNK)   // 391
#define TB (NN / 16)            // 6250 transform blocks (4 waves x 4 nodes)

typedef _Float16 f16;
typedef _Float16 f16x2 __attribute__((ext_vector_type(2)));

__device__ __forceinline__ f16x2 u2h(unsigned u) { return __builtin_bit_cast(f16x2, u); }
__device__ __forceinline__ unsigned h2u(f16x2 h) { return __builtin_bit_cast(unsigned, h); }

#if defined(__has_builtin) && __has_builtin(__builtin_amdgcn_fdot2)
__device__ __forceinline__ float dot2(f16x2 a, f16x2 b, float c) {
    return __builtin_amdgcn_fdot2(a, b, c, false);
}
#else
__device__ __forceinline__ float dot2(f16x2 a, f16x2 b, float c) {
    c = fmaf((float)a.x, (float)b.x, c);
    return fmaf((float)a.y, (float)b.y, c);
}
#endif

// ===================== fp8 (OCP e4m3) helpers (r18, kept) =====================
// r18 result: bytes halved -> only -3%. Gather is NOT byte/line bound; r19
// targets instruction/queue pressure (DS bpermutes + VMEM instr count).

#if defined(__has_builtin)
#if __has_builtin(__builtin_amdgcn_cvt_pk_f32_fp8) && __has_builtin(__builtin_amdgcn_cvt_pk_fp8_f32)
#define HW_FP8 1
#endif
#endif

#ifndef HW_FP8
__device__ __forceinline__ float dec_e4m3(unsigned b) {
    unsigned s = b >> 7, e = (b >> 3) & 0xF, m = b & 7;
    float v;
    if (e == 0) v = (float)m * 0.001953125f;                 // m * 2^-9
    else v = (1.f + (float)m * 0.125f) * exp2f((float)((int)e - 7));
    return s ? -v : v;
}
__device__ __forceinline__ unsigned char enc_e4m3(float x) {
    unsigned s = (__builtin_bit_cast(unsigned, x) >> 31) << 7;
    float a = fabsf(x);
    if (!(a < 464.f)) return (unsigned char)(s | 0x7E);      // clamp / NaN->max
    int e; float m = frexpf(a, &e);                          // a = m*2^e, m in [0.5,1)
    int E = e - 1;
    unsigned bits;
    if (E < -6) {
        int n = (int)rintf(a * 512.f);
        bits = (n > 7) ? 0x08u : (unsigned)n;
    } else {
        int n = (int)rintf((2.f * m - 1.f) * 8.f);
        if (n == 8) { n = 0; E += 1; }
        if (E > 8) return (unsigned char)(s | 0x7E);
        bits = ((unsigned)(E + 7) << 3) | (unsigned)n;
    }
    return (unsigned char)(s | bits);
}
#endif

__device__ __forceinline__ void acc_fp8(unsigned v, float& a0, float& a1,
                                        float& a2, float& a3) {
#ifdef HW_FP8
    auto lo = __builtin_amdgcn_cvt_pk_f32_fp8((int)v, false);
    auto hi = __builtin_amdgcn_cvt_pk_f32_fp8((int)v, true);
    a0 += lo[0]; a1 += lo[1]; a2 += hi[0]; a3 += hi[1];
#else
    a0 += dec_e4m3(v & 0xFFu);         a1 += dec_e4m3((v >> 8) & 0xFFu);
    a2 += dec_e4m3((v >> 16) & 0xFFu); a3 += dec_e4m3(v >> 24);
#endif
}

__device__ __forceinline__ unsigned char enc_fp8(float x) {
#ifdef HW_FP8
    return (unsigned char)(__builtin_amdgcn_cvt_pk_fp8_f32(x, x, 0, false) & 0xFF);
#else
    return enc_e4m3(x);
#endif
}

// ================= merged: CSR placement (blocks 0..NWG-1) ====================
// ================= || layer-0 transform + weight pack (blocks NWG..) ==========

__global__ void mt_kernel(const int* __restrict__ src, const int* __restrict__ dst,
                          int* __restrict__ bfill, unsigned* __restrict__ pairs,
                          const float* __restrict__ h,
                          const float* __restrict__ Wn, const float* __restrict__ bn,
                          const float* __restrict__ Wr,
                          unsigned char* __restrict__ hn8, f16* __restrict__ hrb,
                          const float* __restrict__ Wn1, const float* __restrict__ Wr1,
                          const float* __restrict__ Wn2, const float* __restrict__ Wr2,
                          const float* __restrict__ Wp1, unsigned* __restrict__ w16) {
    __shared__ int lc[BKT];
    __shared__ int lbase[BKT];
    int t = threadIdx.x;

    if (blockIdx.x < NWG) {
        // ---- CSR placement (bucketized; r16 proved random scatter >100us) ----
        for (int b = t; b < BKT; b += 256) lc[b] = 0;
        __syncthreads();
        int base = blockIdx.x * CHUNK;
        int myd[CHUNK / 256];
        int myr[CHUNK / 256];
#pragma unroll
        for (int j = 0; j < CHUNK / 256; ++j) {
            int i = base + j * 256 + t;
            myd[j] = (i < EE) ? dst[i] : -1;
            myr[j] = (myd[j] >= 0) ? atomicAdd(&lc[myd[j] >> 8], 1) : 0;
        }
        __syncthreads();
        for (int b = t; b < BKT; b += 256) {
            int c = lc[b];
            if (c) {
                int ofs = atomicAdd(&bfill[b], c);
                if (ofs + c > SLAB) ofs = SLAB - c;   // statistically unreachable
                lbase[b] = b * SLAB + ofs;
            }
        }
        __syncthreads();
#pragma unroll
        for (int j = 0; j < CHUNK / 256; ++j) {
            int i = base + j * 256 + t;
            if (myd[j] >= 0) {
                int b = myd[j] >> 8;
                pairs[lbase[b] + myr[j]] = (unsigned)src[i] | ((unsigned)(myd[j] & 255) << 24);
            }
        }
        return;
    }

    int bb = blockIdx.x - NWG;

    // ---- f16 weight pack (first 40 transform blocks) ----
    if (bb < 40) {
        int id = bb * 256 + t;
        int mat = id >> 11;            // 0..4
        int p = (id >> 6) & 31;        // pair index
        int j = id & 63;               // output column
        const float* W = (mat == 0) ? Wn1 : (mat == 1) ? Wr1 :
                         (mat == 2) ? Wn2 : (mat == 3) ? Wr2 : Wp1;
        f16x2 v;
        v.x = (f16)W[(2 * p) * HID + j];
        v.y = (f16)W[(2 * p + 1) * HID + j];
        w16[id] = h2u(v);
    }

    // ---- layer-0 transform: 4 nodes/wave, lane = output column ----
    int lane = t & 63;
    int wid = (bb * 256 + t) >> 6;
    int m0 = __builtin_amdgcn_readfirstlane(wid << 2);
    const float* h0 = h + (size_t)m0 * 32;

    float an0 = 0.f, an1 = 0.f, an2 = 0.f, an3 = 0.f;
    float ar0 = 0.f, ar1 = 0.f, ar2 = 0.f, ar3 = 0.f;
#pragma unroll
    for (int k = 0; k < 32; ++k) {
        float wn = Wn[k * HID + lane];
        float wr = Wr[k * HID + lane];
        float hk0 = h0[k], hk1 = h0[32 + k], hk2 = h0[64 + k], hk3 = h0[96 + k];
        an0 = fmaf(hk0, wn, an0); ar0 = fmaf(hk0, wr, ar0);
        an1 = fmaf(hk1, wn, an1); ar1 = fmaf(hk1, wr, ar1);
        an2 = fmaf(hk2, wn, an2); ar2 = fmaf(hk2, wr, ar2);
        an3 = fmaf(hk3, wn, an3); ar3 = fmaf(hk3, wr, ar3);
    }
    float b = bn[lane];
    size_t o8 = (size_t)m0 * HID + lane;        // fp8: 1 byte per feature
    hn8[o8] = enc_fp8(an0);
    hn8[o8 + HID] = enc_fp8(an1);
    hn8[o8 + 2 * HID] = enc_fp8(an2);
    hn8[o8 + 3 * HID] = enc_fp8(an3);
    size_t o = (size_t)m0 * HID + lane;
    hrb[o] = (f16)(ar0 + b); hrb[o + HID] = (f16)(ar1 + b);
    hrb[o + 2 * HID] = (f16)(ar2 + b); hrb[o + 3 * HID] = (f16)(ar3 + b);
}

// ================= per-bucket counting sort (r17 register form) ===============
// r19: per-node segments padded to x4 with sentinel node NN (zero row) so the
// gather can use aligned int4 col loads with no scalar tail. rs/re keep the
// TRUE range; slots [re, rs+pad4) hold NN. inv uses true count.

__global__ void build_kernel(const unsigned* __restrict__ pairs,
                             const int* __restrict__ bfill,
                             int* __restrict__ rs, int* __restrict__ re,
                             float* __restrict__ inv, int* __restrict__ col) {
    __shared__ int ncnt[256];
    __shared__ int nexcl[256];
    int b = blockIdx.x;
    int t = threadIdx.x;
    int s0 = b * SLAB;
    int ce = bfill[b]; if (ce > SLAB) ce = SLAB;
    ncnt[t] = 0;
    __syncthreads();
    unsigned mypk[SLAB_IT];
    int myr[SLAB_IT];
#pragma unroll
    for (int j = 0; j < SLAB_IT; ++j) {
        int e = j * 256 + t;
        if (e < ce) {
            unsigned pk = pairs[s0 + e];
            mypk[j] = pk;
            myr[j] = atomicAdd(&ncnt[pk >> 24], 1);
        }
    }
    __syncthreads();
    int c = ncnt[t];                  // true count
    int c4 = (c + 3) & ~3;            // padded count
    nexcl[t] = c4;
    __syncthreads();
    for (int off = 1; off < 256; off <<= 1) {
        int u = (t >= off) ? nexcl[t - off] : 0;
        __syncthreads();
        nexcl[t] += u;
        __syncthreads();
    }
    int excl = nexcl[t] - c4;         // padded exclusive base
    int node = (b << 8) + t;
    if (node < NN) {
        int start = s0 + excl; if (start > s0 + SLAB) start = s0 + SLAB;
        int end = start + c;   if (end > s0 + SLAB) end = s0 + SLAB;
        rs[node] = start;
        re[node] = end;
        inv[node] = (c > 0) ? (1.0f / (float)c) : 0.0f;
    }
    __syncthreads();
    ncnt[t] = excl;          // repurpose: per-key padded exclusive base
    __syncthreads();
#pragma unroll
    for (int j = 0; j < SLAB_IT; ++j) {
        int e = j * 256 + t;
        if (e < ce) {
            unsigned pk = mypk[j];
            int idx = s0 + ncnt[pk >> 24] + myr[j];
            if (idx < s0 + SLAB) col[idx] = (int)(pk & 0xFFFFFFu);
        }
    }
    // sentinel pads (zero row NN): slots [excl+c, excl+c4)
    for (int k = c; k < c4; ++k) {
        int idx = s0 + excl + k;
        if (idx < s0 + SLAB) col[idx] = NN;
    }
}

// ================= quarter-wave gather, fp8 rows (device helper) ==============
// r19: col segments are x4-padded & 16B-aligned -> int4 col loads (2 VMEM per
// 8-edge batch instead of 8) and no scalar tail in the common path. VMEM
// instrs per batch: 16 -> 10. Row loads unchanged (8-deep, best r12).

__device__ __forceinline__ void qgather8(const unsigned* __restrict__ rp,
                                         const int* __restrict__ col,
                                         int e, int en, int en4, int fl,
                                         float& a0, float& a1, float& a2, float& a3) {
    while (e + 8 <= en4) {
        int4 ca = *(const int4*)(col + e);
        int4 cb = *(const int4*)(col + e + 4);
        unsigned v0 = rp[(size_t)ca.x * 16 + fl];
        unsigned v1 = rp[(size_t)ca.y * 16 + fl];
        unsigned v2 = rp[(size_t)ca.z * 16 + fl];
        unsigned v3 = rp[(size_t)ca.w * 16 + fl];
        unsigned v4 = rp[(size_t)cb.x * 16 + fl];
        unsigned v5 = rp[(size_t)cb.y * 16 + fl];
        unsigned v6 = rp[(size_t)cb.z * 16 + fl];
        unsigned v7 = rp[(size_t)cb.w * 16 + fl];
        acc_fp8(v0, a0, a1, a2, a3);
        acc_fp8(v1, a0, a1, a2, a3);
        acc_fp8(v2, a0, a1, a2, a3);
        acc_fp8(v3, a0, a1, a2, a3);
        acc_fp8(v4, a0, a1, a2, a3);
        acc_fp8(v5, a0, a1, a2, a3);
        acc_fp8(v6, a0, a1, a2, a3);
        acc_fp8(v7, a0, a1, a2, a3);
        e += 8;
    }
    if (e + 4 <= en4) {
        int4 ca = *(const int4*)(col + e);
        unsigned v0 = rp[(size_t)ca.x * 16 + fl];
        unsigned v1 = rp[(size_t)ca.y * 16 + fl];
        unsigned v2 = rp[(size_t)ca.z * 16 + fl];
        unsigned v3 = rp[(size_t)ca.w * 16 + fl];
        acc_fp8(v0, a0, a1, a2, a3);
        acc_fp8(v1, a0, a1, a2, a3);
        acc_fp8(v2, a0, a1, a2, a3);
        acc_fp8(v3, a0, a1, a2, a3);
        e += 4;
    }
    while (e < en) {                  // only reachable if pad clamp fired (15-sigma)
        unsigned v = rp[(size_t)col[e] * 16 + fl];
        acc_fp8(v, a0, a1, a2, a3);
        ++e;
    }
}

// ================= fused gather_k + transform_{k+1} ===========================
// r19 epilogue: the 128 ds_bpermute/wave (__shfl h-broadcast) replaced by
// 1 ds_write_b64 + 32 uniform ds_read_b128 per wave. Same values, same
// accumulation order (kk ascending) -> bitwise-identical dots. Wave-private
// LDS region, same-wave DS ops are in-order -> no barrier needed.

__global__ void gt_kernel(const unsigned char* __restrict__ An8,
                          const int* __restrict__ rs, const int* __restrict__ re,
                          const int* __restrict__ col, const float* __restrict__ inv,
                          f16* C,
                          const unsigned* __restrict__ Wn16, const float* __restrict__ bn,
                          const unsigned* __restrict__ Wr16,
                          unsigned char* __restrict__ Aout8) {
    __shared__ uint4 hsh[128];        // 4 waves x 4 nodes x 8 uint4 = 2KB
    int t = threadIdx.x;
    int lane = t & 63;
    int wv = t >> 6;
    int wid = (blockIdx.x * blockDim.x + t) >> 6;
    int m0 = wid << 2;
    int m = m0 + (lane >> 4);
    int fl = lane & 15;

    int e = rs[m], en = re[m];
    int en4 = e + ((en - e + 3) & ~3);
    int bnd = ((m >> 8) + 1) * SLAB;
    if (en4 > bnd) en4 = bnd;

    float a0 = 0.f, a1 = 0.f, a2 = 0.f, a3 = 0.f;
    qgather8((const unsigned*)An8, col, e, en, en4, fl, a0, a1, a2, a3);

    // h_{k+1}[m] = relu(inv*agg + hrb_k[m]); lane fl holds feats 4fl..4fl+3
    float iv = inv[m];
    uint2 cur = ((const uint2*)C)[(size_t)m * 16 + fl];
    f16x2 q0 = u2h(cur.x), q1 = u2h(cur.y);
    f16x2 hA, hB;
    hA.x = (f16)fmaxf(fmaf(a0, iv, (float)q0.x), 0.f);
    hA.y = (f16)fmaxf(fmaf(a1, iv, (float)q0.y), 0.f);
    hB.x = (f16)fmaxf(fmaf(a2, iv, (float)q1.x), 0.f);
    hB.y = (f16)fmaxf(fmaf(a3, iv, (float)q1.y), 0.f);

    // stage h-rows: node n's dword 2fl = hx, 2fl+1 = hy
    uint2 hv; hv.x = h2u(hA); hv.y = h2u(hB);
    ((uint2*)hsh)[wv * 64 + (lane >> 4) * 16 + fl] = hv;

    float an[4] = {0.f, 0.f, 0.f, 0.f};
    float ar[4] = {0.f, 0.f, 0.f, 0.f};
#pragma unroll
    for (int j = 0; j < 8; ++j) {     // covers kk = 2j, 2j+1
        f16x2 wn0 = u2h(Wn16[(4 * j) * HID + lane]);
        f16x2 wn1 = u2h(Wn16[(4 * j + 1) * HID + lane]);
        f16x2 wn2 = u2h(Wn16[(4 * j + 2) * HID + lane]);
        f16x2 wn3 = u2h(Wn16[(4 * j + 3) * HID + lane]);
        f16x2 wr0 = u2h(Wr16[(4 * j) * HID + lane]);
        f16x2 wr1 = u2h(Wr16[(4 * j + 1) * HID + lane]);
        f16x2 wr2 = u2h(Wr16[(4 * j + 2) * HID + lane]);
        f16x2 wr3 = u2h(Wr16[(4 * j + 3) * HID + lane]);
#pragma unroll
        for (int n = 0; n < 4; ++n) {
            uint4 d = hsh[wv * 32 + n * 8 + j];   // uniform addr -> broadcast
            an[n] = dot2(u2h(d.x), wn0, an[n]);
            an[n] = dot2(u2h(d.y), wn1, an[n]);
            an[n] = dot2(u2h(d.z), wn2, an[n]);
            an[n] = dot2(u2h(d.w), wn3, an[n]);
            ar[n] = dot2(u2h(d.x), wr0, ar[n]);
            ar[n] = dot2(u2h(d.y), wr1, ar[n]);
            ar[n] = dot2(u2h(d.z), wr2, ar[n]);
            ar[n] = dot2(u2h(d.w), wr3, ar[n]);
        }
    }
    float b = bn[lane];
    size_t o8 = (size_t)m0 * HID + lane;
    size_t o = (size_t)m0 * HID + lane;
#pragma unroll
    for (int n = 0; n < 4; ++n) {
        Aout8[o8 + n * HID] = enc_fp8(an[n]);
        C[o + n * HID] = (f16)(ar[n] + b);
    }
}

// ================= fused gather_2 (no relu) + predictor head ==================

__global__ void gh_kernel(const unsigned char* __restrict__ An8,
                          const int* __restrict__ rs, const int* __restrict__ re,
                          const int* __restrict__ col, const float* __restrict__ inv,
                          const f16* __restrict__ C,
                          const unsigned* __restrict__ Wp116, const float* __restrict__ bp1,
                          const float* __restrict__ Wp2, const float* __restrict__ bp2,
                          float* __restrict__ out) {
    __shared__ uint4 hsh[128];
    int t = threadIdx.x;
    int lane = t & 63;
    int wv = t >> 6;
    int wid = (blockIdx.x * blockDim.x + t) >> 6;
    int m0 = wid << 2;
    int m = m0 + (lane >> 4);
    int fl = lane & 15;

    int e = rs[m], en = re[m];
    int en4 = e + ((en - e + 3) & ~3);
    int bnd = ((m >> 8) + 1) * SLAB;
    if (en4 > bnd) en4 = bnd;

    float a0 = 0.f, a1 = 0.f, a2 = 0.f, a3 = 0.f;
    qgather8((const unsigned*)An8, col, e, en, en4, fl, a0, a1, a2, a3);

    float iv = inv[m];
    uint2 cur = ((const uint2*)C)[(size_t)m * 16 + fl];
    f16x2 q0 = u2h(cur.x), q1 = u2h(cur.y);
    f16x2 hA, hB;
    hA.x = (f16)fmaf(a0, iv, (float)q0.x);
    hA.y = (f16)fmaf(a1, iv, (float)q0.y);
    hB.x = (f16)fmaf(a2, iv, (float)q1.x);
    hB.y = (f16)fmaf(a3, iv, (float)q1.y);

    uint2 hv; hv.x = h2u(hA); hv.y = h2u(hB);
    ((uint2*)hsh)[wv * 64 + (lane >> 4) * 16 + fl] = hv;

    float tn[4] = {0.f, 0.f, 0.f, 0.f};
#pragma unroll
    for (int j = 0; j < 8; ++j) {
        f16x2 wp0 = u2h(Wp116[(4 * j) * HID + lane]);
        f16x2 wp1 = u2h(Wp116[(4 * j + 1) * HID + lane]);
        f16x2 wp2 = u2h(Wp116[(4 * j + 2) * HID + lane]);
        f16x2 wp3 = u2h(Wp116[(4 * j + 3) * HID + lane]);
#pragma unroll
        for (int n = 0; n < 4; ++n) {
            uint4 d = hsh[wv * 32 + n * 8 + j];
            tn[n] = dot2(u2h(d.x), wp0, tn[n]);
            tn[n] = dot2(u2h(d.y), wp1, tn[n]);
            tn[n] = dot2(u2h(d.z), wp2, tn[n]);
            tn[n] = dot2(u2h(d.w), wp3, tn[n]);
        }
    }
    float b = bp1[lane], w2v = Wp2[lane];
    float r0 = fmaxf(tn[0] + b, 0.f) * w2v;
    float r1 = fmaxf(tn[1] + b, 0.f) * w2v;
    float r2 = fmaxf(tn[2] + b, 0.f) * w2v;
    float r3 = fmaxf(tn[3] + b, 0.f) * w2v;
#pragma unroll
    for (int off = 32; off > 0; off >>= 1) {
        r0 += __shfl_xor(r0, off);
        r1 += __shfl_xor(r1, off);
        r2 += __shfl_xor(r2, off);
        r3 += __shfl_xor(r3, off);
    }
    if (lane == 0) {
        float bb = bp2[0];
        out[m0]     = 1.f / (1.f + expf(-(r0 + bb)));
        out[m0 + 1] = 1.f / (1.f + expf(-(r1 + bb)));
        out[m0 + 2] = 1.f / (1.f + expf(-(r2 + bb)));
        out[m0 + 3] = 1.f / (1.f + expf(-(r3 + bb)));
    }
}

extern "C" void kernel_launch(void* const* d_in, const int* in_sizes, int n_in,
                              void* d_out, int out_size, void* d_ws, size_t ws_size,
                              hipStream_t stream) {
    const float* x   = (const float*)d_in[0];
    const int* eidx  = (const int*)d_in[1];
    const float* Wn0 = (const float*)d_in[2];
    const float* bn0 = (const float*)d_in[3];
    const float* Wr0 = (const float*)d_in[4];
    const float* Wn1 = (const float*)d_in[5];
    const float* bn1 = (const float*)d_in[6];
    const float* Wr1 = (const float*)d_in[7];
    const float* Wn2 = (const float*)d_in[8];
    const float* bn2 = (const float*)d_in[9];
    const float* Wr2 = (const float*)d_in[10];
    const float* Wp1 = (const float*)d_in[11];
    const float* bp1 = (const float*)d_in[12];
    const float* Wp2 = (const float*)d_in[13];
    const float* bp2 = (const float*)d_in[14];
    float* out = (float*)d_out;

    const int* src = eidx;
    const int* dst = eidx + EE;

    char* w = (char*)d_ws;
    size_t off = 0;
    auto carve = [&](size_t bytes) -> void* {
        void* p = w + off;
        off = (off + bytes + 255) & ~(size_t)255;
        return p;
    };
    int*   rsA    = (int*)carve((size_t)NN * 4);
    int*   reA    = (int*)carve((size_t)NN * 4);
    float* inv    = (float*)carve((size_t)NN * 4);
    int*   col    = (int*)carve((size_t)BKT * SLAB * 4);   // slab layout
    int*   bfill  = (int*)carve((size_t)BKT * 4);
    unsigned* w16 = (unsigned*)carve((size_t)5 * 2048 * 4); // packed f16 weights
    unsigned char* A0 = (unsigned char*)carve((size_t)(NN + 1) * HID); // fp8 + sentinel row
    unsigned char* A1 = (unsigned char*)carve((size_t)(NN + 1) * HID);
    f16*   C      = (f16*)carve((size_t)NN * HID * 2);     // hrb f16 (own-row in place)
    unsigned* pairs = (unsigned*)carve((size_t)BKT * SLAB * 4);
    (void)ws_size;

    unsigned* Wn1_16 = w16;
    unsigned* Wr1_16 = w16 + 2048;
    unsigned* Wn2_16 = w16 + 4096;
    unsigned* Wr2_16 = w16 + 6144;
    unsigned* Wp1_16 = w16 + 8192;

    hipMemsetAsync(bfill, 0, (size_t)BKT * 4, stream);
    // sentinel zero rows (node NN) for x4 padding
    hipMemsetAsync(A0 + (size_t)NN * HID, 0, HID, stream);
    hipMemsetAsync(A1 + (size_t)NN * HID, 0, HID, stream);

    // merged: CSR placement || layer-0 transform (+ weight pack)
    mt_kernel<<<NWG + TB, 256, 0, stream>>>(src, dst, bfill, pairs,
                                            x, Wn0, bn0, Wr0, A0, C,
                                            Wn1, Wr1, Wn2, Wr2, Wp1, w16);
    // per-bucket counting sort (+ x4 sentinel padding)
    build_kernel<<<BKT, 256, 0, stream>>>(pairs, bfill, rsA, reA, inv, col);

    // gather0 + transform1 (reads A0, writes A1 + C)
    gt_kernel<<<TB, 256, 0, stream>>>(A0, rsA, reA, col, inv, C, Wn1_16, bn1, Wr1_16, A1);
    // gather1 + transform2 (reads A1, writes A0 + C)
    gt_kernel<<<TB, 256, 0, stream>>>(A1, rsA, reA, col, inv, C, Wn2_16, bn2, Wr2_16, A0);
    // gather2 + head (reads A0 + C, writes out)
    gh_kernel<<<TB, 256, 0, stream>>>(A0, rsA, reA, col, inv, C, Wp1_16, bp1, Wp2, bp2, out);
}